// Round 1
// baseline (29.808 us; speedup 1.0000x reference)
//
#include <hip/hip_runtime.h>

#define NBINS 256
#define BPS   8      // blocks per sample
#define NT    256    // threads per block (4 waves)
#define NWAVE (NT / 64)

// ---------------- Kernel 1: per-sample histogram ----------------
// grid = B * BPS blocks; each block handles a contiguous chunk of one sample.
__global__ __launch_bounds__(NT) void hist_kernel(const float* __restrict__ x,
                                                  unsigned int* __restrict__ ghist,
                                                  int n_per_sample) {
    __shared__ unsigned int lh[NWAVE][NBINS];
    const int b    = blockIdx.x / BPS;   // sample index
    const int blk  = blockIdx.x % BPS;   // chunk within sample
    const int tid  = threadIdx.x;
    const int wave = tid >> 6;

    // zero the per-wave private histograms
    for (int i = tid; i < NWAVE * NBINS; i += NT)
        ((unsigned int*)lh)[i] = 0u;
    __syncthreads();

    const int chunk = n_per_sample / BPS;            // 196608/8 = 24576 (mult of 4*NT)
    const float4* src = (const float4*)(x + (size_t)b * n_per_sample
                                          + (size_t)blk * chunk);
    const int n4 = chunk >> 2;                       // 6144 float4
    for (int i = tid; i < n4; i += NT) {
        float4 v = src[i];
        int i0 = (int)(v.x * 256.0f); i0 = min(max(i0, 0), NBINS - 1);
        int i1 = (int)(v.y * 256.0f); i1 = min(max(i1, 0), NBINS - 1);
        int i2 = (int)(v.z * 256.0f); i2 = min(max(i2, 0), NBINS - 1);
        int i3 = (int)(v.w * 256.0f); i3 = min(max(i3, 0), NBINS - 1);
        atomicAdd(&lh[wave][i0], 1u);
        atomicAdd(&lh[wave][i1], 1u);
        atomicAdd(&lh[wave][i2], 1u);
        atomicAdd(&lh[wave][i3], 1u);
    }
    __syncthreads();

    // merge waves, one global atomic per bin per block
    for (int bin = tid; bin < NBINS; bin += NT) {
        unsigned int s = 0;
        #pragma unroll
        for (int w = 0; w < NWAVE; ++w) s += lh[w][bin];
        if (s) atomicAdd(&ghist[(size_t)b * NBINS + bin], s);
    }
}

// ---------------- Kernel 2: entropy + squared error per sample ----------------
// grid = B blocks, NBINS threads; thread t owns bin t.
__global__ __launch_bounds__(NBINS) void entropy_kernel(const unsigned int* __restrict__ ghist,
                                                        const float* __restrict__ target,
                                                        float* __restrict__ err,
                                                        float inv_n) {
    const int b   = blockIdx.x;
    const int tid = threadIdx.x;
    unsigned int h = ghist[(size_t)b * NBINS + tid];
    float t = 0.0f;
    if (h > 0u) {
        float p = (float)h * inv_n;
        t = -p * log2f(p);
    }
    #pragma unroll
    for (int off = 32; off > 0; off >>= 1) t += __shfl_down(t, off, 64);
    __shared__ float ws[NBINS / 64];
    if ((tid & 63) == 0) ws[tid >> 6] = t;
    __syncthreads();
    if (tid == 0) {
        float ent = 0.0f;
        #pragma unroll
        for (int w = 0; w < NBINS / 64; ++w) ent += ws[w];
        float d = ent - target[b];
        err[b] = d * d;
    }
}

// ---------------- Kernel 3: mean over B -> d_out[0] ----------------
__global__ __launch_bounds__(128) void finish_kernel(const float* __restrict__ err,
                                                     float* __restrict__ out,
                                                     int B) {
    const int tid = threadIdx.x;
    float t = 0.0f;
    for (int i = tid; i < B; i += 128) t += err[i];
    #pragma unroll
    for (int off = 32; off > 0; off >>= 1) t += __shfl_down(t, off, 64);
    __shared__ float ws[2];
    if ((tid & 63) == 0) ws[tid >> 6] = t;
    __syncthreads();
    if (tid == 0) out[0] = (ws[0] + ws[1]) / (float)B;
}

extern "C" void kernel_launch(void* const* d_in, const int* in_sizes, int n_in,
                              void* d_out, int out_size, void* d_ws, size_t ws_size,
                              hipStream_t stream) {
    const float* x      = (const float*)d_in[0];
    const float* target = (const float*)d_in[1];
    float* out          = (float*)d_out;

    const int B = in_sizes[1];                 // 128
    const int N = in_sizes[0] / B;             // 196608

    unsigned int* ghist = (unsigned int*)d_ws;                 // B*NBINS uints
    float* err = (float*)((char*)d_ws + (size_t)B * NBINS * sizeof(unsigned int));

    // zero the per-sample histograms each call (harness does not re-poison d_ws)
    hipMemsetAsync(ghist, 0, (size_t)B * NBINS * sizeof(unsigned int), stream);

    hist_kernel<<<B * BPS, NT, 0, stream>>>(x, ghist, N);
    entropy_kernel<<<B, NBINS, 0, stream>>>(ghist, target, err, 1.0f / (float)N);
    finish_kernel<<<1, 128, 0, stream>>>(err, out, B);
}

// Round 2
// 24.694 us; speedup vs baseline: 1.2071x; 1.2071x over previous
//
#include <hip/hip_runtime.h>

#define NBINS 256
#define BPS   16     // blocks per sample -> 128*16 = 2048 blocks
#define NT    256    // threads per block (4 waves)
#define NWAVE (NT / 64)

// ---------------- Kernel 1: per-block partial histograms ----------------
// grid = B * BPS blocks; each block histograms a contiguous chunk of one
// sample into LDS (wave-private to cut atomic serialization), then writes
// its 256-bin partial histogram to d_ws with plain coalesced stores.
// No global atomics, no pre-zeroed global memory needed.
__global__ __launch_bounds__(NT) void hist_kernel(const float* __restrict__ x,
                                                  unsigned int* __restrict__ phist,
                                                  int n_per_sample) {
    __shared__ unsigned int lh[NWAVE][NBINS];
    const int tid  = threadIdx.x;
    const int wave = tid >> 6;

    for (int i = tid; i < NWAVE * NBINS; i += NT)
        ((unsigned int*)lh)[i] = 0u;
    __syncthreads();

    const int b     = blockIdx.x / BPS;
    const int blk   = blockIdx.x % BPS;
    const int chunk = n_per_sample / BPS;            // 196608/16 = 12288 (mult of 4*NT)
    const float4* src = (const float4*)(x + (size_t)b * n_per_sample
                                          + (size_t)blk * chunk);
    const int n4 = chunk >> 2;                       // 3072 float4 -> 12 iters/thread
    for (int i = tid; i < n4; i += NT) {
        float4 v = src[i];
        int i0 = (int)(v.x * 256.0f); i0 = min(max(i0, 0), NBINS - 1);
        int i1 = (int)(v.y * 256.0f); i1 = min(max(i1, 0), NBINS - 1);
        int i2 = (int)(v.z * 256.0f); i2 = min(max(i2, 0), NBINS - 1);
        int i3 = (int)(v.w * 256.0f); i3 = min(max(i3, 0), NBINS - 1);
        atomicAdd(&lh[wave][i0], 1u);
        atomicAdd(&lh[wave][i1], 1u);
        atomicAdd(&lh[wave][i2], 1u);
        atomicAdd(&lh[wave][i3], 1u);
    }
    __syncthreads();

    // merge waves -> plain store of this block's partial histogram
    unsigned int* dst = phist + (size_t)blockIdx.x * NBINS;
    for (int bin = tid; bin < NBINS; bin += NT) {
        unsigned int s = 0;
        #pragma unroll
        for (int w = 0; w < NWAVE; ++w) s += lh[w][bin];
        dst[bin] = s;
    }
}

// ---------------- Kernel 2: sum partials -> entropy -> squared error ----------------
// grid = B blocks, NBINS threads; thread t owns bin t.
__global__ __launch_bounds__(NBINS) void entropy_kernel(const unsigned int* __restrict__ phist,
                                                        const float* __restrict__ target,
                                                        float* __restrict__ err,
                                                        float inv_n) {
    const int b   = blockIdx.x;
    const int tid = threadIdx.x;

    const unsigned int* base = phist + (size_t)b * BPS * NBINS;
    unsigned int h = 0;
    #pragma unroll
    for (int k = 0; k < BPS; ++k) h += base[k * NBINS + tid];

    float t = 0.0f;
    if (h > 0u) {
        float p = (float)h * inv_n;
        t = -p * log2f(p);
    }
    #pragma unroll
    for (int off = 32; off > 0; off >>= 1) t += __shfl_down(t, off, 64);
    __shared__ float ws[NBINS / 64];
    if ((tid & 63) == 0) ws[tid >> 6] = t;
    __syncthreads();
    if (tid == 0) {
        float ent = 0.0f;
        #pragma unroll
        for (int w = 0; w < NBINS / 64; ++w) ent += ws[w];
        float d = ent - target[b];
        err[b] = d * d;
    }
}

// ---------------- Kernel 3: mean over B -> d_out[0] ----------------
__global__ __launch_bounds__(128) void finish_kernel(const float* __restrict__ err,
                                                     float* __restrict__ out,
                                                     int B) {
    const int tid = threadIdx.x;
    float t = 0.0f;
    for (int i = tid; i < B; i += 128) t += err[i];
    #pragma unroll
    for (int off = 32; off > 0; off >>= 1) t += __shfl_down(t, off, 64);
    __shared__ float ws[2];
    if ((tid & 63) == 0) ws[tid >> 6] = t;
    __syncthreads();
    if (tid == 0) out[0] = (ws[0] + ws[1]) / (float)B;
}

extern "C" void kernel_launch(void* const* d_in, const int* in_sizes, int n_in,
                              void* d_out, int out_size, void* d_ws, size_t ws_size,
                              hipStream_t stream) {
    const float* x      = (const float*)d_in[0];
    const float* target = (const float*)d_in[1];
    float* out          = (float*)d_out;

    const int B = in_sizes[1];                 // 128
    const int N = in_sizes[0] / B;             // 196608

    unsigned int* phist = (unsigned int*)d_ws;                 // B*BPS*NBINS uints (2 MB)
    float* err = (float*)((char*)d_ws + (size_t)B * BPS * NBINS * sizeof(unsigned int));

    hist_kernel<<<B * BPS, NT, 0, stream>>>(x, phist, N);
    entropy_kernel<<<B, NBINS, 0, stream>>>(phist, target, err, 1.0f / (float)N);
    finish_kernel<<<1, 128, 0, stream>>>(err, out, B);
}